// Round 8
// baseline (1527.799 us; speedup 1.0000x reference)
//
#include <hip/hip_runtime.h>

typedef unsigned short u16;
typedef unsigned int u32;
typedef __bf16 bf16x8 __attribute__((ext_vector_type(8)));
typedef float f32x4 __attribute__((ext_vector_type(4)));

__device__ __forceinline__ float bf2f(u16 h) {
  union { u32 u; float f; } c; c.u = ((u32)h) << 16; return c.f;
}
__device__ __forceinline__ float bflo(u32 u) {
  union { u32 u; float f; } c; c.u = u << 16; return c.f;
}
__device__ __forceinline__ float bfhi(u32 u) {
  union { u32 u; float f; } c; c.u = u & 0xffff0000u; return c.f;
}
// compiler emits packed v_cvt_pk_bf16_f32 for __bf16 casts (RNE)
__device__ __forceinline__ u32 pack2bf(float a, float b) {
  union { __bf16 h[2]; u32 u; } c; c.h[0] = (__bf16)a; c.h[1] = (__bf16)b;
  return c.u;
}
__device__ __forceinline__ u16 f2bf(float f) {
  union { __bf16 h; u16 u; } c; c.h = (__bf16)f; return c.u;
}
__device__ __forceinline__ float relu(float x) { return x > 0.f ? x : 0.f; }

// One-shot conversion of all four weight slices to bf16 [N][Kpad] layouts.
// Ranges: [0,40960) W_i->160 ; [40960,106496) W_h->256 ;
//         [106496,147456) W_o[:, :133]->160 ; [147456,212992) W_o[:,133:]->256
__global__ __launch_bounds__(256) void cvt_all(
    const float* __restrict__ Wi, const float* __restrict__ Wh,
    const float* __restrict__ Wo, u16* __restrict__ dWi, u16* __restrict__ dWh,
    u16* __restrict__ dWo1, u16* __restrict__ dWo2) {
  int i = blockIdx.x * 256 + threadIdx.x;
  if (i < 40960) {
    int n = i / 160, k = i % 160;
    dWi[i] = f2bf(k < 147 ? Wi[n * 147 + k] : 0.f);
  } else if (i < 106496) {
    int j = i - 40960;
    dWh[j] = f2bf(Wh[j]);
  } else if (i < 147456) {
    int j = i - 106496;
    int n = j / 160, k = j % 160;
    dWo1[j] = f2bf(k < 133 ? Wo[n * 389 + k] : 0.f);
  } else {
    int j = i - 147456;
    int n = j / 256, k = j % 256;
    dWo2[j] = f2bf(Wo[n * 389 + 133 + k]);
  }
}

// GEMM: C[M,256] = A[M,K] * W[256,K]^T.  BM=64, BN=256; 4 waves, each
// 64 rows x 64-col band.  A staged COALESCED into LDS once (1 barrier);
// B-fragments read from global (weights L2-resident, broadcast).
// Swapped-operand MFMA: acc = mfma(w_frag, a_frag) -> lane holds 4
// consecutive output columns (c0 = wn + jw*16 + (lane>>4)*4) at row
// m0 + im*16 + (lane&15).  Stores: bf16 = 8B uint2, f32 = 16B float4.
// Output must not alias any input buffer (cross-wave WAR, round-4 lesson).
// ASRC: 0 = A from f32 global [M][Kreal] (k<Kreal guard, converted)
//       1 = A from bf16 global [M][KPAD]
//       2 = A row r = bf16( Ab[idx1[r]] - relu(Ab2[idx2[r]]) )  [KPAD=256]
//       3 = A row r = bf16( sum_{j<6} relu(Ab[idx1[r*6+j]]) )   [KPAD=256]
//           (fused gather_sum, 6 neighbor loads issued together per chunk;
//            if WAMSG, staged rows also stored to amsg_out)
// EPI:  0 = bf16 acc -> outb0
//       1 = v=acc+bias[c]; bf16 v -> outb0; relu(v) f32 -> outf
//       2 = v=acc+bf2f(addb[idx]); bf16 v -> outb0   (pre-activation store)
//       3 = v=acc+bf2f(addb[idx]); relu(v) f32 -> outf
template <int ASRC, int EPI, int KPAD, int WAMSG, int MINW>
__global__ __launch_bounds__(256, MINW) void gemm7(
    const float* __restrict__ Af, int Kreal,
    const u16* __restrict__ Ab, const u16* __restrict__ Ab2,
    const int* __restrict__ idx1, const int* __restrict__ idx2,
    const u16* __restrict__ Bw,
    const u16* __restrict__ addb, const float* __restrict__ bias,
    u16* __restrict__ outb0, float* __restrict__ outf,
    u16* __restrict__ amsg_out) {
  constexpr int LDK = KPAD + 8;  // row stride 336/528B: 2-way bank alias (free)
  __shared__ u16 As[64 * LDK];

  const int tid = threadIdx.x;
  const int lane = tid & 63;
  const int wn = (tid >> 6) * 64;
  const int m0 = blockIdx.x * 64;
  const int lm = lane & 15, lg = lane >> 4;
  const int koff = lg * 8;

  // ---- coalesced staging of A[64][KPAD] ----
  if constexpr (ASRC == 0) {
    // consecutive lanes -> consecutive k pairs (8B apart): coalesced dwords
#pragma unroll
    for (int p = 0; p < 64 * KPAD / 512; ++p) {
      int e = (p * 256 + tid) * 2;
      int row = e / KPAD, k = e % KPAD;
      const float* src = Af + (size_t)(m0 + row) * Kreal + k;
      float x0 = (k < Kreal) ? src[0] : 0.f;
      float x1 = (k + 1 < Kreal) ? src[1] : 0.f;
      *reinterpret_cast<u32*>(&As[row * LDK + k]) = pack2bf(x0, x1);
    }
  } else if constexpr (ASRC == 1) {
    // consecutive lanes -> consecutive 16B chunks: perfectly coalesced
#pragma unroll
    for (int p = 0; p < 64 * KPAD / 8 / 256; ++p) {
      int ch = p * 256 + tid;
      int row = ch / (KPAD / 8), c8 = ch % (KPAD / 8);
      uint4 v = *reinterpret_cast<const uint4*>(Ab + (size_t)(m0 + row) * KPAD + c8 * 8);
      *reinterpret_cast<uint4*>(&As[row * LDK + c8 * 8]) = v;
    }
  } else if constexpr (ASRC == 2) {
    // fused gather-subtract: 4 threads per row, 128B segment each per source
    static_assert(KPAD == 256, "ASRC2 assumes KPAD=256");
    const int row = tid >> 2, seg = tid & 3;
    const int gr = m0 + row;
    const int r1 = idx1[gr], r2 = idx2[gr];
    const u16* pa = Ab + (size_t)r1 * KPAD + seg * 64;
    const u16* pb = Ab2 + (size_t)r2 * KPAD + seg * 64;
    uint4 va[8], vb[8];
#pragma unroll
    for (int i = 0; i < 8; ++i) va[i] = *reinterpret_cast<const uint4*>(pa + i * 8);
#pragma unroll
    for (int i = 0; i < 8; ++i) vb[i] = *reinterpret_cast<const uint4*>(pb + i * 8);
    u16* dst = &As[row * LDK + seg * 64];
#pragma unroll
    for (int i = 0; i < 8; ++i) {
      uint4 o;
      o.x = pack2bf(bflo(va[i].x) - relu(bflo(vb[i].x)),
                    bfhi(va[i].x) - relu(bfhi(vb[i].x)));
      o.y = pack2bf(bflo(va[i].y) - relu(bflo(vb[i].y)),
                    bfhi(va[i].y) - relu(bfhi(vb[i].y)));
      o.z = pack2bf(bflo(va[i].z) - relu(bflo(vb[i].z)),
                    bfhi(va[i].z) - relu(bfhi(vb[i].z)));
      o.w = pack2bf(bflo(va[i].w) - relu(bflo(vb[i].w)),
                    bfhi(va[i].w) - relu(bfhi(vb[i].w)));
      *reinterpret_cast<uint4*>(dst + i * 8) = o;
    }
  } else {
    // fused gather_sum: 8 threads/row (32-u16 seg), 2 passes of 32 rows.
    // Per 8-elem chunk: all 6 neighbor uint4 loads issued together
    // (independent -> MLP); chunk c+1 loads pipeline under chunk c math.
    static_assert(KPAD == 256, "ASRC3 assumes KPAD=256");
#pragma unroll
    for (int pass = 0; pass < 2; ++pass) {
      const int row = pass * 32 + (tid >> 3);
      const int seg = tid & 7;
      const int gr = m0 + row;
      const int* nbp = idx1 + gr * 6;
      int nn[6];
#pragma unroll
      for (int j = 0; j < 6; ++j) nn[j] = nbp[j];
      const u16* base = Ab + seg * 32;
#pragma unroll
      for (int c = 0; c < 4; ++c) {
        const int off = c * 8;
        uint4 v[6];
#pragma unroll
        for (int j = 0; j < 6; ++j)
          v[j] = *reinterpret_cast<const uint4*>(base + (size_t)nn[j] * 256 + off);
        float s[8];
#pragma unroll
        for (int e = 0; e < 8; ++e) s[e] = 0.f;
#pragma unroll
        for (int j = 0; j < 6; ++j) {
          s[0] += relu(bflo(v[j].x)); s[1] += relu(bfhi(v[j].x));
          s[2] += relu(bflo(v[j].y)); s[3] += relu(bfhi(v[j].y));
          s[4] += relu(bflo(v[j].z)); s[5] += relu(bfhi(v[j].z));
          s[6] += relu(bflo(v[j].w)); s[7] += relu(bfhi(v[j].w));
        }
        uint4 o;
        o.x = pack2bf(s[0], s[1]); o.y = pack2bf(s[2], s[3]);
        o.z = pack2bf(s[4], s[5]); o.w = pack2bf(s[6], s[7]);
        *reinterpret_cast<uint4*>(&As[row * LDK + seg * 32 + off]) = o;
        if constexpr (WAMSG)
          *reinterpret_cast<uint4*>(amsg_out + (size_t)gr * 256 + seg * 32 + off) = o;
      }
    }
  }
  __syncthreads();

  f32x4 acc[4][4];
#pragma unroll
  for (int i = 0; i < 4; ++i)
#pragma unroll
    for (int j = 0; j < 4; ++j) acc[i][j] = (f32x4)(0.f);

#pragma unroll
  for (int kk = 0; kk < KPAD / 32; ++kk) {
    const int k0 = kk * 32 + koff;
    bf16x8 a[4];
#pragma unroll
    for (int im = 0; im < 4; ++im)
      a[im] = *reinterpret_cast<const bf16x8*>(&As[(im * 16 + lm) * LDK + k0]);
#pragma unroll
    for (int jw = 0; jw < 4; ++jw) {
      bf16x8 b = *reinterpret_cast<const bf16x8*>(
          Bw + (size_t)(wn + jw * 16 + lm) * KPAD + k0);
#pragma unroll
      for (int im = 0; im < 4; ++im)
        acc[im][jw] = __builtin_amdgcn_mfma_f32_16x16x32_bf16(b, a[im], acc[im][jw], 0, 0, 0);
    }
  }

#pragma unroll
  for (int im = 0; im < 4; ++im) {
#pragma unroll
    for (int jw = 0; jw < 4; ++jw) {
      const int r = m0 + im * 16 + lm;
      const int c0 = wn + jw * 16 + lg * 4;
      const size_t idx = (size_t)r * 256 + c0;
      f32x4 v = acc[im][jw];
      if constexpr (EPI == 0) {
        uint2 o; o.x = pack2bf(v[0], v[1]); o.y = pack2bf(v[2], v[3]);
        *reinterpret_cast<uint2*>(outb0 + idx) = o;
      } else if constexpr (EPI == 1) {
        const float4 bb = *reinterpret_cast<const float4*>(bias + c0);
        v[0] += bb.x; v[1] += bb.y; v[2] += bb.z; v[3] += bb.w;
        uint2 o; o.x = pack2bf(v[0], v[1]); o.y = pack2bf(v[2], v[3]);
        *reinterpret_cast<uint2*>(outb0 + idx) = o;
        float4 rl = {relu(v[0]), relu(v[1]), relu(v[2]), relu(v[3])};
        *reinterpret_cast<float4*>(outf + idx) = rl;
      } else if constexpr (EPI == 2) {
        const uint2 ab = *reinterpret_cast<const uint2*>(addb + idx);
        v[0] += bflo(ab.x); v[1] += bfhi(ab.x);
        v[2] += bflo(ab.y); v[3] += bfhi(ab.y);
        uint2 o; o.x = pack2bf(v[0], v[1]); o.y = pack2bf(v[2], v[3]);
        *reinterpret_cast<uint2*>(outb0 + idx) = o;
      } else {
        const uint2 ab = *reinterpret_cast<const uint2*>(addb + idx);
        v[0] += bflo(ab.x); v[1] += bfhi(ab.x);
        v[2] += bflo(ab.y); v[3] += bfhi(ab.y);
        float4 rl = {relu(v[0]), relu(v[1]), relu(v[2]), relu(v[3])};
        *reinterpret_cast<float4*>(outf + idx) = rl;
      }
    }
  }
}

__global__ __launch_bounds__(256) void mol_mean(const float* __restrict__ dfin,
                                                float* __restrict__ out) {
  int mol = blockIdx.x, c = threadIdx.x;
  const float* p = dfin + (size_t)mol * (42 * 256) + c;
  float s = 0.f;
#pragma unroll
  for (int a = 0; a < 42; ++a) s += p[a * 256];
  out[(size_t)mol * 256 + c] = s * (1.0f / 42.0f);
}

extern "C" void kernel_launch(void* const* d_in, const int* in_sizes, int n_in,
                              void* d_out, int out_size, void* d_ws,
                              size_t ws_size, hipStream_t stream) {
  const float* f_atoms = (const float*)d_in[0];
  const float* f_bonds = (const float*)d_in[1];
  const float* W_i = (const float*)d_in[2];
  const float* W_h = (const float*)d_in[3];
  const float* W_o = (const float*)d_in[4];
  const float* b_o = (const float*)d_in[5];
  const int* a2b = (const int*)d_in[6];
  const int* b2a = (const int*)d_in[7];
  const int* b2revb = (const int*)d_in[8];

  const int NA = 168000, NB = 360000, H = 256;
  const size_t SZ_BH = (size_t)NB * H * 2;
  const size_t SZ_AH = (size_t)NA * H * 2;

  char* ws = (char*)d_ws;
  u16* inp_b = (u16*)ws;  ws += SZ_BH;   // S_0 (pre-act bond state = inp)
  u16* P0    = (u16*)ws;  ws += SZ_BH;   // S_1
  u16* P1    = (u16*)ws;  ws += SZ_BH;   // S_2
  u16* amsg  = (u16*)ws;  ws += SZ_AH;
  u16* base_b = (u16*)ws; ws += SZ_AH;
  u16* Wi_b  = (u16*)ws;  ws += 256 * 160 * 2;
  u16* Wh_b  = (u16*)ws;  ws += 256 * 256 * 2;
  u16* Wo1_b = (u16*)ws;  ws += 256 * 160 * 2;
  u16* Wo2_b = (u16*)ws;  ws += 256 * 256 * 2;

  float* out = (float*)d_out;
  float* d0 = out;
  float* d1 = d0 + (size_t)NA * H;
  float* d2 = d1 + (size_t)NA * H;
  float* dfin = d2 + (size_t)NA * H;
  float* mol = dfin + (size_t)NA * H;

  dim3 blk(256);
  cvt_all<<<dim3(832), blk, 0, stream>>>(W_i, W_h, W_o, Wi_b, Wh_b, Wo1_b, Wo2_b);

  // inp = f_bonds @ W_i^T  (pre-activation; relu fused into consumers)
  gemm7<0, 0, 160, 0, 4><<<dim3(NB / 64), blk, 0, stream>>>(
      f_bonds, 147, nullptr, nullptr, nullptr, nullptr, Wi_b,
      nullptr, nullptr, inp_b, nullptr, nullptr);
  // base = f_atoms @ W_o1^T + b_o (pre-relu, bf16) ; d0 = relu(base) f32
  gemm7<0, 1, 160, 0, 4><<<dim3(NA / 64), blk, 0, stream>>>(
      f_atoms, 133, nullptr, nullptr, nullptr, nullptr, Wo1_b,
      nullptr, b_o, base_b, d0, nullptr);

  u16* S = inp_b;
  u16* pms[2] = {P0, P1};
  float* douts[3] = {d1, d2, dfin};
  for (int d = 0; d < 3; ++d) {
    if (d < 2) {
      // d_{d+1} = relu(base + (gather-sum) @ W_o2^T); amsg written as side-out
      gemm7<3, 3, 256, 1, 4><<<dim3(NA / 64), blk, 0, stream>>>(
          nullptr, 0, S, nullptr, a2b, nullptr, Wo2_b,
          base_b, nullptr, nullptr, douts[d], amsg);
      // S' = inp + (amsg[b2a] - relu(S[b2revb])) @ W_h^T  (gather fused)
      gemm7<2, 2, 256, 0, 3><<<dim3(NB / 64), blk, 0, stream>>>(
          nullptr, 0, amsg, S, b2a, b2revb, Wh_b,
          inp_b, nullptr, pms[d], nullptr, nullptr);
      S = pms[d];
    } else {
      gemm7<3, 3, 256, 0, 4><<<dim3(NA / 64), blk, 0, stream>>>(
          nullptr, 0, S, nullptr, a2b, nullptr, Wo2_b,
          base_b, nullptr, nullptr, douts[d], nullptr);
    }
  }
  mol_mean<<<dim3(4000), blk, 0, stream>>>(dfin, mol);
}